// Round 1
// baseline (78.202 us; speedup 1.0000x reference)
//
#include <hip/hip_runtime.h>
#include <math.h>

// Problem constants (from setup_inputs): matrices are [n, n, B] f32.
constexpr int N = 64;       // n (rows and cols)
constexpr int B = 256;      // batch (innermost, contiguous)
constexpr int BCHUNK = 64;  // b's per block
constexpr int JG = 8;       // j rows per thread
constexpr int THREADS = 512; // 64 b-lanes x 8 j-groups

// Zero/seed outputs (d_out is poisoned 0xAA before every timed launch).
__global__ void init_out_kernel(float* out) {
    out[0] = 0.0f; // loss accumulator
    out[1] = 0.0f; // correction_num accumulator
}

__global__ __launch_bounds__(THREADS)
void pm_hinge_kernel(const float* __restrict__ outm,
                     const float* __restrict__ labm,
                     const float* __restrict__ margin,
                     float* __restrict__ dout)
{
    // LDS slabs: [j][b] layout, b contiguous. 2 x 16KB = 32KB.
    __shared__ float o_s[N * BCHUNK];
    __shared__ float l_s[N * BCHUNK];
    __shared__ float wsum[THREADS / 64];

    const int r  = blockIdx.x;       // row index 0..63
    const int b0 = blockIdx.y * BCHUNK;
    const int t  = threadIdx.x;

    // ---- Stage global -> LDS: per matrix 64j x 64b floats = 1024 float4.
    // float4 f: j = f>>4, b4 = (f&15)*4. Coalesced 256B runs per j-row.
    const float* src_o = outm + (size_t)r * (N * B) + b0;
    const float* src_l = labm + (size_t)r * (N * B) + b0;
#pragma unroll
    for (int f = t; f < (N * BCHUNK) / 4; f += THREADS) {
        const int j  = f >> 4;
        const int b4 = (f & 15) * 4;
        const float4 vo = *(const float4*)(src_o + j * B + b4);
        const float4 vl = *(const float4*)(src_l + j * B + b4);
        *(float4*)(&o_s[j * BCHUNK + b4]) = vo;
        *(float4*)(&l_s[j * BCHUNK + b4]) = vl;
    }
    __syncthreads();

    const float m  = margin[0];
    const int   b  = t & 63;   // lane id == b offset -> 2-way LDS aliasing (free)
    const int   jg = t >> 6;   // wave id == j-group

    // Cache this thread's 8 j-row values in registers.
    float oj[JG], lj[JG];
#pragma unroll
    for (int i = 0; i < JG; ++i) {
        oj[i] = o_s[(jg * JG + i) * BCHUNK + b];
        lj[i] = l_s[(jg * JG + i) * BCHUNK + b];
    }

    // ---- Main loop: 64 k-iters, 2 LDS reads each, 8 terms per iter.
    float acc = 0.0f;
#pragma unroll 4
    for (int k = 0; k < N; ++k) {
        const float ok = o_s[k * BCHUNK + b];
        const float lk = l_s[k * BCHUNK + b];
#pragma unroll
        for (int i = 0; i < JG; ++i) {
            const float d    = oj[i] - ok;
            const float dl   = lj[i] - lk;
            const float term = fmaf(-d, dl, m); // m - d*dl
            acc += fmaxf(term, 0.0f);
        }
    }

    // ---- argmax-equality count: wave 0 only (one lane per b).
    if (t < 64) {
        const int bb = t;
        float bo = o_s[bb]; int io = 0;
        float bl = l_s[bb]; int il = 0;
#pragma unroll 4
        for (int j = 1; j < N; ++j) {
            const float vo = o_s[j * BCHUNK + bb];
            if (vo > bo) { bo = vo; io = j; }
            const float vl = l_s[j * BCHUNK + bb];
            if (vl > bl) { bl = vl; il = j; }
        }
        const unsigned long long mask = __ballot(io == il);
        if (bb == 0) atomicAdd(dout + 1, (float)__popcll(mask));
    }

    // ---- loss reduction: wave shuffle, then per-block sum, one atomic.
#pragma unroll
    for (int off = 32; off > 0; off >>= 1)
        acc += __shfl_down(acc, off, 64);
    if (b == 0) wsum[jg] = acc;
    __syncthreads();
    if (t == 0) {
        float s = 0.0f;
#pragma unroll
        for (int w = 0; w < THREADS / 64; ++w) s += wsum[w];
        atomicAdd(dout, s);
    }
}

extern "C" void kernel_launch(void* const* d_in, const int* in_sizes, int n_in,
                              void* d_out, int out_size, void* d_ws, size_t ws_size,
                              hipStream_t stream) {
    const float* outm   = (const float*)d_in[0];
    const float* labm   = (const float*)d_in[1];
    const float* margin = (const float*)d_in[2];
    float* out = (float*)d_out;

    init_out_kernel<<<1, 1, 0, stream>>>(out);
    pm_hinge_kernel<<<dim3(N, B / BCHUNK), THREADS, 0, stream>>>(outm, labm, margin, out);
}

// Round 2
// 68.658 us; speedup vs baseline: 1.1390x; 1.1390x over previous
//
#include <hip/hip_runtime.h>
#include <math.h>

// Problem: out_matrix, label_matrix [n=64, n=64, B=256] f32.
// loss = sum_{b,r,j,k} relu(m - (o[r,j,b]-o[r,k,b])*(l[r,j,b]-l[r,k,b]))
// Symmetric in (j,k); diagonal = relu(m). So loss = 2*S_upper + N*N*B*relu(m).
// cnt = #{(b,r): argmax_j o[r,j,b] == argmax_j l[r,j,b]}

constexpr int N = 64;        // n
constexpr int B = 256;       // batch (contiguous innermost)
constexpr int BCHUNK = 64;   // b's per block (== wave width -> jg wave-uniform)
constexpr int NJG = 16;      // j-groups (one per wave)
constexpr int JI = 4;        // j's per thread: j_i = jg + 16*i
constexpr int THREADS = BCHUNK * NJG;       // 1024
constexpr int NBLK = N * (B / BCHUNK);      // 256 partials

__global__ __launch_bounds__(THREADS)
void pm_hinge_partial(const float* __restrict__ outm,
                      const float* __restrict__ labm,
                      const float* __restrict__ margin,
                      float* __restrict__ ws)
{
    __shared__ float o_s[N * BCHUNK];   // [j][b], 16 KB
    __shared__ float l_s[N * BCHUNK];
    __shared__ float wsum[NJG];

    const int r   = blockIdx.x;
    const int b0  = blockIdx.y * BCHUNK;
    const int t   = threadIdx.x;
    const int blk = blockIdx.y * N + r;   // 0..255

    // Stage global -> LDS (coalesced float4; 2 iters/thread).
    const float* src_o = outm + (size_t)r * (N * B) + b0;
    const float* src_l = labm + (size_t)r * (N * B) + b0;
#pragma unroll
    for (int f = t; f < (N * BCHUNK) / 4; f += THREADS) {
        const int j  = f >> 4;
        const int b4 = (f & 15) * 4;
        *(float4*)(&o_s[j * BCHUNK + b4]) = *(const float4*)(src_o + j * B + b4);
        *(float4*)(&l_s[j * BCHUNK + b4]) = *(const float4*)(src_l + j * B + b4);
    }
    __syncthreads();

    const float m  = margin[0];
    const int   b  = t & 63;   // lane id == b -> 2-way LDS bank aliasing (free)
    const int   jg = t >> 6;   // wave id == j-group (wave-uniform)

    float oj[JI], lj[JI];
#pragma unroll
    for (int i = 0; i < JI; ++i) {
        oj[i] = o_s[(jg + NJG * i) * BCHUNK + b];
        lj[i] = l_s[(jg + NJG * i) * BCHUNK + b];
    }

    // Strict upper triangle only, balanced by strided j-assignment.
    // Regime m (0..3): k in [jg+16m+1, jg+16m+16] (m=3 clips at 63) has
    // exactly m+1 of this thread's j's with j < k. Wave-uniform bounds.
    float acc = 0.0f;

#define TERM(i) acc += fmaxf(fmaf(-(oj[i] - ok), lj[i] - lk, m), 0.0f)

#pragma unroll 4
    for (int k = jg + 1; k <= jg + 16; ++k) {
        const float ok = o_s[k * BCHUNK + b], lk = l_s[k * BCHUNK + b];
        TERM(0);
    }
#pragma unroll 4
    for (int k = jg + 17; k <= jg + 32; ++k) {
        const float ok = o_s[k * BCHUNK + b], lk = l_s[k * BCHUNK + b];
        TERM(0); TERM(1);
    }
#pragma unroll 4
    for (int k = jg + 33; k <= jg + 48; ++k) {
        const float ok = o_s[k * BCHUNK + b], lk = l_s[k * BCHUNK + b];
        TERM(0); TERM(1); TERM(2);
    }
#pragma unroll 2
    for (int k = jg + 49; k < N; ++k) {
        const float ok = o_s[k * BCHUNK + b], lk = l_s[k * BCHUNK + b];
        TERM(0); TERM(1); TERM(2); TERM(3);
    }
#undef TERM

    // argmax-equality count for this block's 64 b's (wave 0 only).
    float cnt = 0.0f;
    if (t < 64) {
        const int bb = t;
        float bo = o_s[bb]; int io = 0;
        float bl = l_s[bb]; int il = 0;
#pragma unroll 4
        for (int j = 1; j < N; ++j) {
            const float vo = o_s[j * BCHUNK + bb];
            if (vo > bo) { bo = vo; io = j; }
            const float vl = l_s[j * BCHUNK + bb];
            if (vl > bl) { bl = vl; il = j; }
        }
        const unsigned long long mask = __ballot(io == il);
        cnt = (float)__popcll(mask);
    }

    // Per-wave shuffle reduce, then per-block sum -> partials in ws.
#pragma unroll
    for (int off = 32; off > 0; off >>= 1)
        acc += __shfl_down(acc, off, 64);
    if (b == 0) wsum[jg] = acc;
    __syncthreads();
    if (t == 0) {
        float s = 0.0f;
#pragma unroll
        for (int w = 0; w < NJG; ++w) s += wsum[w];
        ws[blk] = s;             // upper-triangle partial
        ws[NBLK + blk] = cnt;    // argmax-equality partial
    }
}

// One wave: fold 256+256 partials, apply symmetry factor + diagonal.
__global__ __launch_bounds__(64)
void pm_hinge_reduce(const float* __restrict__ ws,
                     const float* __restrict__ margin,
                     float* __restrict__ dout)
{
    const int t = threadIdx.x;
    float s = 0.0f, c = 0.0f;
#pragma unroll
    for (int i = 0; i < NBLK / 64; ++i) {
        s += ws[t + 64 * i];
        c += ws[NBLK + t + 64 * i];
    }
#pragma unroll
    for (int off = 32; off > 0; off >>= 1) {
        s += __shfl_down(s, off, 64);
        c += __shfl_down(c, off, 64);
    }
    if (t == 0) {
        const float m = margin[0];
        dout[0] = 2.0f * s + (float)(N * (size_t)N * B) * fmaxf(m, 0.0f);
        dout[1] = c;
    }
}

extern "C" void kernel_launch(void* const* d_in, const int* in_sizes, int n_in,
                              void* d_out, int out_size, void* d_ws, size_t ws_size,
                              hipStream_t stream) {
    const float* outm   = (const float*)d_in[0];
    const float* labm   = (const float*)d_in[1];
    const float* margin = (const float*)d_in[2];
    float* out = (float*)d_out;
    float* ws  = (float*)d_ws;

    pm_hinge_partial<<<dim3(N, B / BCHUNK), THREADS, 0, stream>>>(outm, labm, margin, ws);
    pm_hinge_reduce<<<1, 64, 0, stream>>>(ws, margin, out);
}